// Round 1
// baseline (339.688 us; speedup 1.0000x reference)
//
#include <hip/hip_runtime.h>
#include <hip/hip_bf16.h>
#include <stdint.h>

typedef __bf16 bf16x8 __attribute__((ext_vector_type(8)));
typedef float f32x4 __attribute__((ext_vector_type(4)));

#define MFMA16(a, b, c) __builtin_amdgcn_mfma_f32_16x16x32_bf16((a), (b), (c), 0, 0, 0)

// fp32 -> bf16 RNE
__device__ __forceinline__ ushort f2bf(float f) {
  union { float f; uint32_t u; } a; a.f = f;
  uint32_t u = a.u;
  return (ushort)((u + 0x7fffu + ((u >> 16) & 1u)) >> 16);
}

// global -> LDS direct DMA, 16B per lane. LDS dest must be wave-uniform.
__device__ __forceinline__ void glds16(const void* g, void* l) {
  __builtin_amdgcn_global_load_lds(
      (const __attribute__((address_space(1))) uint32_t*)g,
      (__attribute__((address_space(3))) uint32_t*)l, 16, 0, 0);
}

// ---------------------------------------------------------------- convert
__global__ __launch_bounds__(256) void cvt_f32_bf16(const float* __restrict__ in,
                                                    ushort* __restrict__ out, int n) {
  int i = (blockIdx.x * 256 + threadIdx.x) * 4;
  if (i >= n) return;
  float4 v = *(const float4*)(in + i);
  ushort4 o;
  o.x = f2bf(v.x); o.y = f2bf(v.y); o.z = f2bf(v.z); o.w = f2bf(v.w);
  *(ushort4*)(out + i) = o;
}

// ---------------------------------------------------------------- GEMM (B^T)
// out[m][n] = sum_k A[m][k] * Bw[n][k].  N fixed = 1024. M multiple of 128.
// EPI 0: bf16 out [M][1024], * scale
// EPI 1: bf16 out scattered to vT layout (B,H,D,L) = (2,16,64,4096)
// EPI 2: f32 out [M][1024] + bias
template <int EPI>
__global__ __launch_bounds__(256) void gemm_bt(
    const ushort* __restrict__ A, const ushort* __restrict__ Bw,
    void* __restrict__ Cout, int K, float scale, const float* __restrict__ bias) {
  constexpr int NN = 1024;
  __shared__ ushort ldsA[128 * 32];
  __shared__ ushort ldsB[128 * 32];
  __shared__ ushort ldsT[(EPI == 1) ? (4 * 64 * 64) : 8];

  const int tid = threadIdx.x;
  const int w = tid >> 6, l = tid & 63;
  const int wm = w >> 1, wn = w & 1;
  const int m0 = blockIdx.x * 128, n0 = blockIdx.y * 128;

  f32x4 acc[4][4] = {};

  const int srow = l >> 2;      // 16 rows per wave-issue (4 chunks of 16B per 64B row)
  const int schunk = l & 3;

  for (int kt = 0; kt < K; kt += 32) {
#pragma unroll
    for (int r = 0; r < 2; ++r) {
      const int rb = r * 64 + w * 16;           // wave-uniform row base
      const int row = rb + srow;
      const int j = schunk ^ ((row >> 1) & 3);  // pre-swizzled global source chunk
      glds16(A + (size_t)(m0 + row) * K + kt + j * 8, (char*)ldsA + rb * 64);
      glds16(Bw + (size_t)(n0 + row) * K + kt + j * 8, (char*)ldsB + rb * 64);
    }
    __syncthreads();
    bf16x8 af[4], bfr[4];
#pragma unroll
    for (int t = 0; t < 4; ++t) {
      {
        const int rt = wm * 64 + t * 16 + (l & 15);
        const int j = (l >> 4) ^ ((rt >> 1) & 3);
        af[t] = *(const bf16x8*)((const char*)ldsA + rt * 64 + j * 16);
      }
      {
        const int rt = wn * 64 + t * 16 + (l & 15);
        const int j = (l >> 4) ^ ((rt >> 1) & 3);
        bfr[t] = *(const bf16x8*)((const char*)ldsB + rt * 64 + j * 16);
      }
    }
#pragma unroll
    for (int am = 0; am < 4; ++am)
#pragma unroll
      for (int bn = 0; bn < 4; ++bn)
        acc[am][bn] = MFMA16(af[am], bfr[bn], acc[am][bn]);
    __syncthreads();
  }

  if constexpr (EPI == 0) {
#pragma unroll
    for (int am = 0; am < 4; ++am)
#pragma unroll
      for (int bn = 0; bn < 4; ++bn)
#pragma unroll
        for (int i = 0; i < 4; ++i) {
          const int row = m0 + wm * 64 + am * 16 + (l >> 4) * 4 + i;
          const int col = n0 + wn * 64 + bn * 16 + (l & 15);
          ((ushort*)Cout)[(size_t)row * NN + col] = f2bf(acc[am][bn][i] * scale);
        }
  } else if constexpr (EPI == 2) {
#pragma unroll
    for (int am = 0; am < 4; ++am)
#pragma unroll
      for (int bn = 0; bn < 4; ++bn)
#pragma unroll
        for (int i = 0; i < 4; ++i) {
          const int row = m0 + wm * 64 + am * 16 + (l >> 4) * 4 + i;
          const int col = n0 + wn * 64 + bn * 16 + (l & 15);
          ((float*)Cout)[(size_t)row * NN + col] = acc[am][bn][i] + bias[col];
        }
  } else {
    // EPI 1: transpose 64x64 wave tile in LDS, then coalesced stores along L.
    ushort* tp = ldsT + w * 4096;
#pragma unroll
    for (int am = 0; am < 4; ++am)
#pragma unroll
      for (int bn = 0; bn < 4; ++bn)
#pragma unroll
        for (int i = 0; i < 4; ++i) {
          const int ml = am * 16 + (l >> 4) * 4 + i;
          const int cl = bn * 16 + (l & 15);
          tp[cl * 64 + ml] = f2bf(acc[am][bn][i]);
        }
    __syncthreads();
#pragma unroll
    for (int it = 0; it < 8; ++it) {
      const int cl = it * 8 + (l >> 3);
      const int mc = l & 7;
      bf16x8 vv = *(const bf16x8*)(tp + cl * 64 + mc * 8);
      const int gcol = n0 + wn * 64 + cl;   // 0..1023 -> (h,d)
      const int gm = m0 + wm * 64 + mc * 8; // 0..8191 -> (b,l_)
      const int b = gm >> 12;
      const int l_ = gm & 4095;
      const int h = gcol >> 6, d = gcol & 63;
      *(bf16x8*)((ushort*)Cout + (((size_t)b * 16 + h) * 64 + d) * 4096 + l_) = vv;
    }
  }
}

// ---------------------------------------------------------------- fused attention
// q: (B,N,H,D) bf16, pre-scaled by SCALE*log2e.  k: (B,L,H,D).  vT: (B,H,D,L).
// out ao: (B,N,H,D) bf16.  Block: 4 waves, 64 q-rows (16/wave). Loop L in 64-tiles.
__global__ __launch_bounds__(256) void attn_fused(
    const ushort* __restrict__ qb, const ushort* __restrict__ kb,
    const ushort* __restrict__ vT, ushort* __restrict__ ao) {
  constexpr int H = 16, D = 64, L = 4096, N = 1024;
  __shared__ ushort ldsK[64 * 64];
  __shared__ ushort ldsV[64 * 64];
  __shared__ ushort ldsP[4 * 16 * 64];

  const int tid = threadIdx.x, w = tid >> 6, l = tid & 63;
  const int bh = blockIdx.y;
  const int b = bh >> 4, h = bh & 15;
  const int n0 = blockIdx.x * 64;

  // Q fragments in registers (wave's 16 rows x 64 d = 2 K-steps)
  bf16x8 qf[2];
  {
    const int qrow = n0 + w * 16 + (l & 15);
    const ushort* qp = qb + (((size_t)b * N + qrow) * H + h) * D + (l >> 4) * 8;
    qf[0] = *(const bf16x8*)qp;
    qf[1] = *(const bf16x8*)(qp + 32);
  }

  f32x4 oacc[4] = {};
  float m_run[4], l_run[4];
#pragma unroll
  for (int i = 0; i < 4; ++i) { m_run[i] = -1e30f; l_run[i] = 0.f; }

  for (int l0 = 0; l0 < L; l0 += 64) {
    __syncthreads();  // previous tile's LDS reads complete
    // stage K (rows=l, 64x64) and V (rows=d, 64x64), swizzled source chunks
#pragma unroll
    for (int r = 0; r < 2; ++r) {
      const int rb = w * 16 + r * 8;   // wave-uniform: 8 rows per issue (128B rows)
      const int row = rb + (l >> 3);
      const int j = (l & 7) ^ (row & 7);
      glds16(kb + (((size_t)b * L + l0 + row) * H + h) * D + j * 8, (char*)ldsK + rb * 128);
      glds16(vT + ((size_t)(b * H + h) * D + row) * L + l0 + j * 8, (char*)ldsV + rb * 128);
    }
    __syncthreads();

    // S = Q K^T (16 rows x 64 l-cols per wave)
    f32x4 sacc[4] = {};
#pragma unroll
    for (int c = 0; c < 4; ++c) {
      const int rt = c * 16 + (l & 15);
#pragma unroll
      for (int ks = 0; ks < 2; ++ks) {
        const int j = ks * 4 + (l >> 4);
        bf16x8 kf = *(const bf16x8*)((const char*)ldsK + rt * 128 + ((j ^ (rt & 7)) << 4));
        sacc[c] = MFMA16(qf[ks], kf, sacc[c]);
      }
    }

    // online softmax (exp2 space; SCALE*log2e folded into q)
    float corr[4];
#pragma unroll
    for (int i = 0; i < 4; ++i) {
      float mt = fmaxf(fmaxf(sacc[0][i], sacc[1][i]), fmaxf(sacc[2][i], sacc[3][i]));
#pragma unroll
      for (int dd = 1; dd < 16; dd <<= 1) mt = fmaxf(mt, __shfl_xor(mt, dd, 64));
      const float mn = fmaxf(m_run[i], mt);
      corr[i] = __builtin_amdgcn_exp2f(m_run[i] - mn);
      float rs = 0.f;
#pragma unroll
      for (int c = 0; c < 4; ++c) {
        const float p = __builtin_amdgcn_exp2f(sacc[c][i] - mn);
        sacc[c][i] = p;
        rs += p;
      }
#pragma unroll
      for (int dd = 1; dd < 16; dd <<= 1) rs += __shfl_xor(rs, dd, 64);
      l_run[i] = l_run[i] * corr[i] + rs;
      m_run[i] = mn;
    }
#pragma unroll
    for (int c = 0; c < 4; ++c)
#pragma unroll
      for (int i = 0; i < 4; ++i) oacc[c][i] *= corr[i];

    // P (D-layout) -> wave-private LDS tile [16][64], swizzled, as bf16
    ushort* pp = ldsP + w * 1024;
#pragma unroll
    for (int c = 0; c < 4; ++c)
#pragma unroll
      for (int i = 0; i < 4; ++i) {
        const int row = (l >> 4) * 4 + i;
        const int col = c * 16 + (l & 15);
        *(ushort*)((char*)pp + row * 128 + ((((col >> 3) ^ (row & 7))) << 4) + ((col & 7) << 1)) =
            f2bf(sacc[c][i]);
      }
    asm volatile("s_waitcnt lgkmcnt(0)" ::: "memory");
    __builtin_amdgcn_sched_barrier(0);

    // O += P V  (A = P rows n, k = l;  B = vT rows d, k = l)
    bf16x8 pf[2];
#pragma unroll
    for (int ks = 0; ks < 2; ++ks) {
      const int rt = l & 15;
      const int j = ks * 4 + (l >> 4);
      pf[ks] = *(const bf16x8*)((const char*)pp + rt * 128 + ((j ^ (rt & 7)) << 4));
    }
#pragma unroll
    for (int c = 0; c < 4; ++c) {
      const int rt = c * 16 + (l & 15);
#pragma unroll
      for (int ks = 0; ks < 2; ++ks) {
        const int j = ks * 4 + (l >> 4);
        bf16x8 vf = *(const bf16x8*)((const char*)ldsV + rt * 128 + ((j ^ (rt & 7)) << 4));
        oacc[c] = MFMA16(pf[ks], vf, oacc[c]);
      }
    }
  }

  // epilogue: O / l_run -> ao (B,N,H,D)
#pragma unroll
  for (int c = 0; c < 4; ++c)
#pragma unroll
    for (int i = 0; i < 4; ++i) {
      const int n = n0 + w * 16 + (l >> 4) * 4 + i;
      const int d = c * 16 + (l & 15);
      ao[(((size_t)b * N + n) * H + h) * D + d] = f2bf(oacc[c][i] / l_run[i]);
    }
}

// ---------------------------------------------------------------- launch
extern "C" void kernel_launch(void* const* d_in, const int* in_sizes, int n_in,
                              void* d_out, int out_size, void* d_ws, size_t ws_size,
                              hipStream_t stream) {
  const float* x  = (const float*)d_in[0];  // (2,1024,1024)
  const float* y  = (const float*)d_in[1];  // (2,4096,1024)
  const float* Wq = (const float*)d_in[2];
  const float* Wk = (const float*)d_in[3];
  const float* Wv = (const float*)d_in[4];
  const float* Wp = (const float*)d_in[5];
  const float* bp = (const float*)d_in[6];
  float* out = (float*)d_out;

  const int B = 2, N = 1024, L = 4096, C = 1024;
  const size_t M1 = 1u << 20;
  ushort* wsb = (ushort*)d_ws;
  ushort* xb  = wsb;             // 2M elems
  ushort* yb  = wsb + 2 * M1;    // 8M
  ushort* wqb = wsb + 10 * M1;   // 1M
  ushort* wkb = wsb + 11 * M1;
  ushort* wvb = wsb + 12 * M1;
  ushort* wpb = wsb + 13 * M1;
  ushort* qbf = wsb + 14 * M1;   // 2M
  ushort* kbf = wsb + 16 * M1;   // 8M
  ushort* vtb = wsb + 24 * M1;   // 8M
  ushort* aob = wsb + 32 * M1;   // 2M  (total 34M elems = 68 MB)

  const int nx = B * N * C, ny = B * L * C, nw = C * C;
  cvt_f32_bf16<<<nx / 1024, 256, 0, stream>>>(x, xb, nx);
  cvt_f32_bf16<<<ny / 1024, 256, 0, stream>>>(y, yb, ny);
  cvt_f32_bf16<<<nw / 1024, 256, 0, stream>>>(Wq, wqb, nw);
  cvt_f32_bf16<<<nw / 1024, 256, 0, stream>>>(Wk, wkb, nw);
  cvt_f32_bf16<<<nw / 1024, 256, 0, stream>>>(Wv, wvb, nw);
  cvt_f32_bf16<<<nw / 1024, 256, 0, stream>>>(Wp, wpb, nw);

  const float qscale = 0.125f * 1.4426950408889634f;  // SCALE * log2(e)
  gemm_bt<0><<<dim3(16, 8), 256, 0, stream>>>(xb, wqb, qbf, C, qscale, nullptr);
  gemm_bt<0><<<dim3(64, 8), 256, 0, stream>>>(yb, wkb, kbf, C, 1.0f, nullptr);
  gemm_bt<1><<<dim3(64, 8), 256, 0, stream>>>(yb, wvb, vtb, C, 1.0f, nullptr);

  attn_fused<<<dim3(16, 32), 256, 0, stream>>>(qbf, kbf, vtb, aob);

  gemm_bt<2><<<dim3(16, 8), 256, 0, stream>>>(aob, wpb, out, C, 1.0f, bp);
}

// Round 3
// 290.488 us; speedup vs baseline: 1.1694x; 1.1694x over previous
//
#include <hip/hip_runtime.h>
#include <hip/hip_bf16.h>
#include <stdint.h>

typedef __bf16 bf16x8 __attribute__((ext_vector_type(8)));
typedef float f32x4 __attribute__((ext_vector_type(4)));

#define MFMA16(a, b, c) __builtin_amdgcn_mfma_f32_16x16x32_bf16((a), (b), (c), 0, 0, 0)

// fp32 -> bf16 RNE
__device__ __forceinline__ ushort f2bf(float f) {
  union { float f; uint32_t u; } a; a.f = f;
  uint32_t u = a.u;
  return (ushort)((u + 0x7fffu + ((u >> 16) & 1u)) >> 16);
}

// global -> LDS direct DMA, 16B per lane. LDS dest must be wave-uniform.
__device__ __forceinline__ void glds16(const void* g, void* l) {
  __builtin_amdgcn_global_load_lds(
      (const __attribute__((address_space(1))) uint32_t*)g,
      (__attribute__((address_space(3))) uint32_t*)l, 16, 0, 0);
}

// ---------------------------------------------------------------- converts
// x (2048 blocks of 1024 elems) then y (8192 blocks)
__global__ __launch_bounds__(256) void cvt_xy(const float* __restrict__ x,
                                              const float* __restrict__ y,
                                              ushort* __restrict__ xb,
                                              ushort* __restrict__ yb) {
  const int bid = blockIdx.x;
  const float* in;
  ushort* out;
  int i;
  if (bid < 2048) { in = x; out = xb; i = bid * 1024 + threadIdx.x * 4; }
  else            { in = y; out = yb; i = (bid - 2048) * 1024 + threadIdx.x * 4; }
  float4 v = *(const float4*)(in + i);
  ushort4 o;
  o.x = f2bf(v.x); o.y = f2bf(v.y); o.z = f2bf(v.z); o.w = f2bf(v.w);
  *(ushort4*)(out + i) = o;
}

// 4 weight matrices, 1M elems each (1024 blocks each)
__global__ __launch_bounds__(256) void cvt_w(
    const float* __restrict__ a, const float* __restrict__ b,
    const float* __restrict__ c, const float* __restrict__ d,
    ushort* __restrict__ oa, ushort* __restrict__ ob,
    ushort* __restrict__ oc, ushort* __restrict__ od) {
  const int bid = blockIdx.x;
  const int sel = bid >> 10;
  const int i = (bid & 1023) * 1024 + threadIdx.x * 4;
  const float* in = (sel == 0) ? a : (sel == 1) ? b : (sel == 2) ? c : d;
  ushort* out = (sel == 0) ? oa : (sel == 1) ? ob : (sel == 2) ? oc : od;
  float4 v = *(const float4*)(in + i);
  ushort4 o;
  o.x = f2bf(v.x); o.y = f2bf(v.y); o.z = f2bf(v.z); o.w = f2bf(v.w);
  *(ushort4*)(out + i) = o;
}

// ---------------------------------------------------------------- GEMM (B^T)
// out[m][n] = sum_k A[m][k] * Bw[n][k].  N fixed = 1024. M multiple of BM.
// EPI 0: bf16 out [M][1024], * scale
// EPI 1: bf16 out scattered to vT layout (B,H,D,L) = (2,16,64,4096)  (BM=128 only)
// EPI 2: f32 out [M][1024] + bias
template <int EPI, int BM>
__global__ __launch_bounds__(256) void gemm_bt(
    const ushort* __restrict__ A, const ushort* __restrict__ Bw,
    void* __restrict__ Cout, int K, float scale, const float* __restrict__ bias) {
  constexpr int NN = 1024;
  constexpr int WM = BM / 2;    // rows per m-wave
  constexpr int AM = WM / 16;   // A fragments / acc-m per wave
  __shared__ ushort ldsA[BM * 32];
  __shared__ ushort ldsB[128 * 32];
  __shared__ ushort ldsT[(EPI == 1) ? (4 * 64 * 64) : 8];

  const int tid = threadIdx.x;
  const int w = tid >> 6, l = tid & 63;
  const int wm = w >> 1, wn = w & 1;
  const int m0 = blockIdx.x * BM, n0 = blockIdx.y * 128;

  f32x4 acc[AM][4] = {};

  const int srow = l >> 2;      // 16 rows per wave-issue (4 chunks of 16B per 64B row)
  const int schunk = l & 3;

  for (int kt = 0; kt < K; kt += 32) {
#pragma unroll
    for (int r = 0; r < BM / 64; ++r) {
      const int rb = r * 64 + w * 16;           // wave-uniform row base
      const int row = rb + srow;
      const int j = schunk ^ ((row >> 1) & 3);  // pre-swizzled global source chunk
      glds16(A + (size_t)(m0 + row) * K + kt + j * 8, (char*)ldsA + rb * 64);
    }
#pragma unroll
    for (int r = 0; r < 2; ++r) {
      const int rb = r * 64 + w * 16;
      const int row = rb + srow;
      const int j = schunk ^ ((row >> 1) & 3);
      glds16(Bw + (size_t)(n0 + row) * K + kt + j * 8, (char*)ldsB + rb * 64);
    }
    __syncthreads();
    bf16x8 af[AM], bfr[4];
#pragma unroll
    for (int t = 0; t < AM; ++t) {
      const int rt = wm * WM + t * 16 + (l & 15);
      const int j = (l >> 4) ^ ((rt >> 1) & 3);
      af[t] = *(const bf16x8*)((const char*)ldsA + rt * 64 + j * 16);
    }
#pragma unroll
    for (int t = 0; t < 4; ++t) {
      const int rt = wn * 64 + t * 16 + (l & 15);
      const int j = (l >> 4) ^ ((rt >> 1) & 3);
      bfr[t] = *(const bf16x8*)((const char*)ldsB + rt * 64 + j * 16);
    }
#pragma unroll
    for (int am = 0; am < AM; ++am)
#pragma unroll
      for (int bn = 0; bn < 4; ++bn)
        acc[am][bn] = MFMA16(af[am], bfr[bn], acc[am][bn]);
    __syncthreads();
  }

  if constexpr (EPI == 0) {
#pragma unroll
    for (int am = 0; am < AM; ++am)
#pragma unroll
      for (int bn = 0; bn < 4; ++bn)
#pragma unroll
        for (int i = 0; i < 4; ++i) {
          const int row = m0 + wm * WM + am * 16 + (l >> 4) * 4 + i;
          const int col = n0 + wn * 64 + bn * 16 + (l & 15);
          ((ushort*)Cout)[(size_t)row * NN + col] = f2bf(acc[am][bn][i] * scale);
        }
  } else if constexpr (EPI == 2) {
#pragma unroll
    for (int am = 0; am < AM; ++am)
#pragma unroll
      for (int bn = 0; bn < 4; ++bn)
#pragma unroll
        for (int i = 0; i < 4; ++i) {
          const int row = m0 + wm * WM + am * 16 + (l >> 4) * 4 + i;
          const int col = n0 + wn * 64 + bn * 16 + (l & 15);
          ((float*)Cout)[(size_t)row * NN + col] = acc[am][bn][i] + bias[col];
        }
  } else {
    // EPI 1: transpose 64x64 wave tile in LDS, then coalesced stores along L.
    ushort* tp = ldsT + w * 4096;
#pragma unroll
    for (int am = 0; am < AM; ++am)
#pragma unroll
      for (int bn = 0; bn < 4; ++bn)
#pragma unroll
        for (int i = 0; i < 4; ++i) {
          const int ml = am * 16 + (l >> 4) * 4 + i;
          const int cl = bn * 16 + (l & 15);
          tp[cl * 64 + ml] = f2bf(acc[am][bn][i]);
        }
    __syncthreads();
#pragma unroll
    for (int it = 0; it < 8; ++it) {
      const int cl = it * 8 + (l >> 3);
      const int mc = l & 7;
      bf16x8 vv = *(const bf16x8*)(tp + cl * 64 + mc * 8);
      const int gcol = n0 + wn * 64 + cl;   // 0..1023 -> (h,d)
      const int gm = m0 + wm * WM + mc * 8; // 0..8191 -> (b,l_)
      const int b = gm >> 12;
      const int l_ = gm & 4095;
      const int h = gcol >> 6, d = gcol & 63;
      *(bf16x8*)((ushort*)Cout + (((size_t)b * 16 + h) * 64 + d) * 4096 + l_) = vv;
    }
  }
}

// ---------------------------------------------------------------- fused attention
// q: (B,N,H,D) bf16, pre-scaled by SCALE*log2e.  k: (B,L,H,D).  vT: (B,H,D,L).
// out ao: (B,N,H,D) bf16.
// 512 blocks (1D, XCD-swizzled), 4 waves, 64 q-rows/block (16/wave).
// KV tile = 128, double-buffered via global_load_lds + counted vmcnt + raw s_barrier.
__global__ __launch_bounds__(256) void attn_fused(
    const ushort* __restrict__ qb, const ushort* __restrict__ kb,
    const ushort* __restrict__ vT, ushort* __restrict__ ao) {
  constexpr int H = 16, D = 64, L = 4096, N = 1024, KB = 128;
  __shared__ ushort ldsK[2][KB * 64];   // [l][d]  128B rows, 8 chunks, swz ^(row&7)
  __shared__ ushort ldsV[2][64 * KB];   // [d][l]  256B rows, 16 chunks, swz ^(row&15)
  __shared__ ushort ldsP[4 * 16 * KB];  // per-wave [16][128], swz ^row

  const int tid = threadIdx.x, w = tid >> 6, l = tid & 63;
  // XCD swizzle: 512 blocks = 8 XCDs x 64; each XCD owns 4 (b,h) values.
  const int wg = blockIdx.x;
  const int v = (wg & 7) * 64 + (wg >> 3);
  const int bh = v >> 4;
  const int n0 = (v & 15) * 64;
  const int b = bh >> 4, h = bh & 15;

  // Q fragments in registers (wave's 16 rows x 64 d = 2 k-chunks)
  bf16x8 qf[2];
  {
    const int qrow = n0 + w * 16 + (l & 15);
    const ushort* qp = qb + (((size_t)b * N + qrow) * H + h) * D + (l >> 4) * 8;
    qf[0] = *(const bf16x8*)qp;
    qf[1] = *(const bf16x8*)(qp + 32);
  }

  f32x4 oacc[4] = {};
  float m_run[4], l_run[4];
#pragma unroll
  for (int i = 0; i < 4; ++i) { m_run[i] = -1e30f; l_run[i] = 0.f; }

  // per-tile staging: 8 glds16 per wave (4 K + 4 V)
  auto stage = [&](int buf, int l0) {
#pragma unroll
    for (int r = 0; r < 4; ++r) {
      const int rb = (w * 4 + r) * 8;          // wave-uniform; 8 rows of 128B
      const int row = rb + (l >> 3);
      const int j = (l & 7) ^ (row & 7);
      glds16(kb + (((size_t)b * L + l0 + row) * H + h) * D + j * 8,
             (char*)ldsK[buf] + rb * 128);
    }
#pragma unroll
    for (int r = 0; r < 4; ++r) {
      const int rb = (w * 4 + r) * 4;          // wave-uniform; 4 rows of 256B
      const int row = rb + (l >> 4);
      const int j = (l & 15) ^ (row & 15);
      glds16(vT + ((size_t)(b * H + h) * D + row) * L + l0 + j * 8,
             (char*)ldsV[buf] + rb * 256);
    }
  };

  stage(0, 0);

  for (int t = 0; t < L / KB; ++t) {
    const int buf = t & 1;
    if (t < L / KB - 1) {
      stage(buf ^ 1, (t + 1) * KB);
      asm volatile("s_waitcnt vmcnt(8)" ::: "memory");  // tile t's 8 loads done
    } else {
      asm volatile("s_waitcnt vmcnt(0)" ::: "memory");
    }
    __builtin_amdgcn_sched_barrier(0);
    __builtin_amdgcn_s_barrier();
    __builtin_amdgcn_sched_barrier(0);

    // S = Q K^T : 16 rows x 128 cols per wave
    f32x4 sacc[8] = {};
#pragma unroll
    for (int c = 0; c < 8; ++c) {
      const int rt = c * 16 + (l & 15);
#pragma unroll
      for (int ks = 0; ks < 2; ++ks) {
        const int j = ks * 4 + (l >> 4);
        bf16x8 kf = *(const bf16x8*)((const char*)ldsK[buf] + rt * 128 + ((j ^ (rt & 7)) << 4));
        sacc[c] = MFMA16(qf[ks], kf, sacc[c]);
      }
    }

    // online softmax (exp2 space; SCALE*log2e folded into q)
    float corr[4];
#pragma unroll
    for (int i = 0; i < 4; ++i) {
      float mt = sacc[0][i];
#pragma unroll
      for (int c = 1; c < 8; ++c) mt = fmaxf(mt, sacc[c][i]);
#pragma unroll
      for (int dd = 1; dd < 16; dd <<= 1) mt = fmaxf(mt, __shfl_xor(mt, dd, 64));
      const float mn = fmaxf(m_run[i], mt);
      corr[i] = __builtin_amdgcn_exp2f(m_run[i] - mn);
      float rs = 0.f;
#pragma unroll
      for (int c = 0; c < 8; ++c) {
        const float p = __builtin_amdgcn_exp2f(sacc[c][i] - mn);
        sacc[c][i] = p;
        rs += p;
      }
#pragma unroll
      for (int dd = 1; dd < 16; dd <<= 1) rs += __shfl_xor(rs, dd, 64);
      l_run[i] = l_run[i] * corr[i] + rs;
      m_run[i] = mn;
    }
#pragma unroll
    for (int c = 0; c < 4; ++c)
#pragma unroll
      for (int i = 0; i < 4; ++i) oacc[c][i] *= corr[i];

    // P (D-layout) -> wave-private LDS [16][128] swizzled bf16
    ushort* pp = ldsP + w * 2048;
#pragma unroll
    for (int c = 0; c < 8; ++c)
#pragma unroll
      for (int i = 0; i < 4; ++i) {
        const int row = (l >> 4) * 4 + i;
        const int col = c * 16 + (l & 15);
        *(ushort*)((char*)pp + row * 256 + (((col >> 3) ^ row) << 4) + ((col & 7) << 1)) =
            f2bf(sacc[c][i]);
      }
    asm volatile("s_waitcnt lgkmcnt(0)" ::: "memory");
    __builtin_amdgcn_sched_barrier(0);

    // O += P V  (A = P rows n, k = l;  B = vT rows d, k = l)
    bf16x8 pf[4];
#pragma unroll
    for (int ks = 0; ks < 4; ++ks) {
      const int rt = l & 15;
      const int j = ks * 4 + (l >> 4);
      pf[ks] = *(const bf16x8*)((const char*)pp + rt * 256 + ((j ^ rt) << 4));
    }
#pragma unroll
    for (int c = 0; c < 4; ++c) {
      const int rt = c * 16 + (l & 15);
#pragma unroll
      for (int ks = 0; ks < 4; ++ks) {
        const int j = ks * 4 + (l >> 4);
        bf16x8 vf = *(const bf16x8*)((const char*)ldsV[buf] + rt * 256 + ((j ^ (rt & 15)) << 4));
        oacc[c] = MFMA16(pf[ks], vf, oacc[c]);
      }
    }
    __builtin_amdgcn_sched_barrier(0);
    __builtin_amdgcn_s_barrier();   // all waves done reading buf before next DMA overwrites it
    __builtin_amdgcn_sched_barrier(0);
  }

  // epilogue: O / l_run -> ao (B,N,H,D)
#pragma unroll
  for (int c = 0; c < 4; ++c)
#pragma unroll
    for (int i = 0; i < 4; ++i) {
      const int n = n0 + w * 16 + (l >> 4) * 4 + i;
      const int d = c * 16 + (l & 15);
      ao[(((size_t)b * N + n) * H + h) * D + d] = f2bf(oacc[c][i] / l_run[i]);
    }
}

// ---------------------------------------------------------------- launch
extern "C" void kernel_launch(void* const* d_in, const int* in_sizes, int n_in,
                              void* d_out, int out_size, void* d_ws, size_t ws_size,
                              hipStream_t stream) {
  const float* x  = (const float*)d_in[0];  // (2,1024,1024)
  const float* y  = (const float*)d_in[1];  // (2,4096,1024)
  const float* Wq = (const float*)d_in[2];
  const float* Wk = (const float*)d_in[3];
  const float* Wv = (const float*)d_in[4];
  const float* Wp = (const float*)d_in[5];
  const float* bp = (const float*)d_in[6];
  float* out = (float*)d_out;

  const size_t M1 = 1u << 20;
  ushort* wsb = (ushort*)d_ws;
  ushort* xb  = wsb;             // 2M elems
  ushort* yb  = wsb + 2 * M1;    // 8M
  ushort* wqb = wsb + 10 * M1;   // 1M
  ushort* wkb = wsb + 11 * M1;
  ushort* wvb = wsb + 12 * M1;
  ushort* wpb = wsb + 13 * M1;
  ushort* qbf = wsb + 14 * M1;   // 2M
  ushort* kbf = wsb + 16 * M1;   // 8M
  ushort* vtb = wsb + 24 * M1;   // 8M
  ushort* aob = wsb + 32 * M1;   // 2M  (total 34M elems = 68 MB)

  cvt_xy<<<10240, 256, 0, stream>>>(x, y, xb, yb);
  cvt_w<<<4096, 256, 0, stream>>>(Wq, Wk, Wv, Wp, wqb, wkb, wvb, wpb);

  const float qscale = 0.125f * 1.4426950408889634f;  // SCALE * log2(e)
  gemm_bt<0, 64><<<dim3(32, 8), 256, 0, stream>>>(xb, wqb, qbf, 1024, qscale, nullptr);
  gemm_bt<0, 128><<<dim3(64, 8), 256, 0, stream>>>(yb, wkb, kbf, 1024, 1.0f, nullptr);
  gemm_bt<1, 128><<<dim3(64, 8), 256, 0, stream>>>(yb, wvb, vtb, 1024, 1.0f, nullptr);

  attn_fused<<<512, 256, 0, stream>>>(qbf, kbf, vtb, aob);

  gemm_bt<2, 64><<<dim3(32, 8), 256, 0, stream>>>(aob, wpb, out, 1024, 1.0f, bp);
}

// Round 4
// 262.628 us; speedup vs baseline: 1.2934x; 1.1061x over previous
//
#include <hip/hip_runtime.h>
#include <hip/hip_bf16.h>
#include <stdint.h>

typedef __bf16 bf16x8 __attribute__((ext_vector_type(8)));
typedef __bf16 bf16x4 __attribute__((ext_vector_type(4)));
typedef float f32x4 __attribute__((ext_vector_type(4)));

#define MFMA16(a, b, c) __builtin_amdgcn_mfma_f32_16x16x32_bf16((a), (b), (c), 0, 0, 0)
#define SB() __builtin_amdgcn_sched_barrier(0)

// fp32 -> bf16 RNE
__device__ __forceinline__ ushort f2bf(float f) {
  union { float f; uint32_t u; } a; a.f = f;
  uint32_t u = a.u;
  return (ushort)((u + 0x7fffu + ((u >> 16) & 1u)) >> 16);
}

// global -> LDS direct DMA, 16B per lane. LDS dest must be wave-uniform.
__device__ __forceinline__ void glds16(const void* g, void* l) {
  __builtin_amdgcn_global_load_lds(
      (const __attribute__((address_space(1))) uint32_t*)g,
      (__attribute__((address_space(3))) uint32_t*)l, 16, 0, 0);
}

// ---------------------------------------------------------------- converts
__global__ __launch_bounds__(256) void cvt_xy(const float* __restrict__ x,
                                              const float* __restrict__ y,
                                              ushort* __restrict__ xb,
                                              ushort* __restrict__ yb) {
  const int bid = blockIdx.x;
  const float* in;
  ushort* out;
  int i;
  if (bid < 2048) { in = x; out = xb; i = bid * 1024 + threadIdx.x * 4; }
  else            { in = y; out = yb; i = (bid - 2048) * 1024 + threadIdx.x * 4; }
  float4 v = *(const float4*)(in + i);
  ushort4 o;
  o.x = f2bf(v.x); o.y = f2bf(v.y); o.z = f2bf(v.z); o.w = f2bf(v.w);
  *(ushort4*)(out + i) = o;
}

__global__ __launch_bounds__(256) void cvt_w(
    const float* __restrict__ a, const float* __restrict__ b,
    const float* __restrict__ c, const float* __restrict__ d,
    ushort* __restrict__ oa, ushort* __restrict__ ob,
    ushort* __restrict__ oc, ushort* __restrict__ od) {
  const int bid = blockIdx.x;
  const int sel = bid >> 10;
  const int i = (bid & 1023) * 1024 + threadIdx.x * 4;
  const float* in = (sel == 0) ? a : (sel == 1) ? b : (sel == 2) ? c : d;
  ushort* out = (sel == 0) ? oa : (sel == 1) ? ob : (sel == 2) ? oc : od;
  float4 v = *(const float4*)(in + i);
  ushort4 o;
  o.x = f2bf(v.x); o.y = f2bf(v.y); o.z = f2bf(v.z); o.w = f2bf(v.w);
  *(ushort4*)(out + i) = o;
}

// ---------------------------------------------------------------- GEMM (B^T)
// out[m][n] = sum_k A[m][k] * Bw[n][k].  Double-buffered LDS, T3-min pipeline:
// stage(next) -> ds_read+MFMA(cur) -> vmcnt(0) -> barrier.  One barrier/K-step.
// EPI 0: bf16 out [M][1024], * scale
// EPI 1: bf16 out scattered to vT layout (B,H,D,L) = (2,16,64,4096)  (128x128 only)
// EPI 2: f32 out [M][1024] + bias
template <int EPI, int BM, int BN>
__global__ __launch_bounds__(256) void gemm_bt(
    const ushort* __restrict__ A, const ushort* __restrict__ Bw,
    void* __restrict__ Cout, int K, float scale, const float* __restrict__ bias) {
  constexpr int NN = 1024;
  constexpr int WM = BM / 2, WN = BN / 2;
  constexpr int AM = WM / 16, BNF = WN / 16;
  __shared__ ushort ldsA[2][BM * 32];
  __shared__ ushort ldsB[2][BN * 32];
  __shared__ ushort ldsT[(EPI == 1) ? (4 * 64 * 64) : 8];

  const int tid = threadIdx.x;
  const int w = tid >> 6, l = tid & 63;
  const int wm = w >> 1, wn = w & 1;
  const int m0 = blockIdx.x * BM, n0 = blockIdx.y * BN;

  f32x4 acc[AM][BNF] = {};

  const int srow = l >> 2;      // 16 rows per wave-issue (4 chunks of 16B per 64B row)
  const int schunk = l & 3;

  auto stage = [&](int buf, int kt) {
#pragma unroll
    for (int r = 0; r < BM / 64; ++r) {
      const int rb = r * 64 + w * 16;           // wave-uniform row base
      const int row = rb + srow;
      const int j = schunk ^ ((row >> 1) & 3);  // pre-swizzled global source chunk
      glds16(A + (size_t)(m0 + row) * K + kt + j * 8, (char*)&ldsA[buf][0] + rb * 64);
    }
#pragma unroll
    for (int r = 0; r < BN / 64; ++r) {
      const int rb = r * 64 + w * 16;
      const int row = rb + srow;
      const int j = schunk ^ ((row >> 1) & 3);
      glds16(Bw + (size_t)(n0 + row) * K + kt + j * 8, (char*)&ldsB[buf][0] + rb * 64);
    }
  };

  const int nt = K / 32;
  stage(0, 0);
  asm volatile("s_waitcnt vmcnt(0)" ::: "memory");
  SB(); __builtin_amdgcn_s_barrier(); SB();

  for (int t = 0; t < nt; ++t) {
    const int buf = t & 1;
    if (t + 1 < nt) stage(buf ^ 1, (t + 1) * 32);
    bf16x8 af[AM], bfr[BNF];
#pragma unroll
    for (int a = 0; a < AM; ++a) {
      const int rt = wm * WM + a * 16 + (l & 15);
      const int j = (l >> 4) ^ ((rt >> 1) & 3);
      af[a] = *(const bf16x8*)((const char*)&ldsA[buf][0] + rt * 64 + j * 16);
    }
#pragma unroll
    for (int bx = 0; bx < BNF; ++bx) {
      const int rt = wn * WN + bx * 16 + (l & 15);
      const int j = (l >> 4) ^ ((rt >> 1) & 3);
      bfr[bx] = *(const bf16x8*)((const char*)&ldsB[buf][0] + rt * 64 + j * 16);
    }
#pragma unroll
    for (int am = 0; am < AM; ++am)
#pragma unroll
      for (int bn = 0; bn < BNF; ++bn)
        acc[am][bn] = MFMA16(af[am], bfr[bn], acc[am][bn]);
    if (t + 1 < nt) {
      asm volatile("s_waitcnt vmcnt(0)" ::: "memory");
      SB(); __builtin_amdgcn_s_barrier(); SB();
    }
  }

  if constexpr (EPI == 0) {
#pragma unroll
    for (int am = 0; am < AM; ++am)
#pragma unroll
      for (int bn = 0; bn < BNF; ++bn)
#pragma unroll
        for (int i = 0; i < 4; ++i) {
          const int row = m0 + wm * WM + am * 16 + (l >> 4) * 4 + i;
          const int col = n0 + wn * WN + bn * 16 + (l & 15);
          ((ushort*)Cout)[(size_t)row * NN + col] = f2bf(acc[am][bn][i] * scale);
        }
  } else if constexpr (EPI == 2) {
#pragma unroll
    for (int am = 0; am < AM; ++am)
#pragma unroll
      for (int bn = 0; bn < BNF; ++bn)
#pragma unroll
        for (int i = 0; i < 4; ++i) {
          const int row = m0 + wm * WM + am * 16 + (l >> 4) * 4 + i;
          const int col = n0 + wn * WN + bn * 16 + (l & 15);
          ((float*)Cout)[(size_t)row * NN + col] = acc[am][bn][i] + bias[col];
        }
  } else {
    // EPI 1: transpose 64x64 wave tile in LDS, then coalesced stores along L.
    ushort* tp = ldsT + w * 4096;
#pragma unroll
    for (int am = 0; am < AM; ++am)
#pragma unroll
      for (int bn = 0; bn < BNF; ++bn)
#pragma unroll
        for (int i = 0; i < 4; ++i) {
          const int ml = am * 16 + (l >> 4) * 4 + i;
          const int cl = bn * 16 + (l & 15);
          tp[cl * 64 + ml] = f2bf(acc[am][bn][i]);
        }
    __syncthreads();
#pragma unroll
    for (int it = 0; it < 8; ++it) {
      const int cl = it * 8 + (l >> 3);
      const int mc = l & 7;
      bf16x8 vv = *(const bf16x8*)(tp + cl * 64 + mc * 8);
      const int gcol = n0 + wn * WN + cl;   // 0..1023 -> (h,d)
      const int gm = m0 + wm * WM + mc * 8; // 0..8191 -> (b,l_)
      const int b = gm >> 12;
      const int l_ = gm & 4095;
      const int h = gcol >> 6, d = gcol & 63;
      *(bf16x8*)((ushort*)Cout + (((size_t)b * 16 + h) * 64 + d) * 4096 + l_) = vv;
    }
  }
}

// ---------------------------------------------------------------- fused attention
// Swapped QK^T: S^T = mfma(A=K, B=Q) so each lane owns one q-row (q=lane&15)
// with 32 S-values in registers -> in-lane softmax, 2 shfl_xor reduce, P stays
// in registers as the PV A-fragment (no LDS P tile).  V B-fragment read as two
// ds_read_b64 matching P's k->l permutation.
__global__ __launch_bounds__(256) void attn_fused(
    const ushort* __restrict__ qb, const ushort* __restrict__ kb,
    const ushort* __restrict__ vT, ushort* __restrict__ ao) {
  constexpr int H = 16, D = 64, L = 4096, N = 1024, KB = 128;
  __shared__ ushort ldsK[2][KB * 64];   // [l][d]  128B rows, 8 chunks, swz ^(row&7)
  __shared__ ushort ldsV[2][64 * KB];   // [d][l]  256B rows, 16 chunks, swz ^(row&15)

  const int tid = threadIdx.x, w = tid >> 6, l = tid & 63;
  // XCD swizzle: 512 blocks = 8 XCDs x 64; each XCD owns 4 (b,h) values.
  const int wg = blockIdx.x;
  const int v = (wg & 7) * 64 + (wg >> 3);
  const int bh = v >> 4;
  const int n0 = (v & 15) * 64;
  const int b = bh >> 4, h = bh & 15;
  const int hq = l >> 4;   // lane quadrant

  // Q fragments (B-operand): lane holds q-row = n0 + w*16 + (lane&15)
  bf16x8 qf[2];
  {
    const int qrow = n0 + w * 16 + (l & 15);
    const ushort* qp = qb + (((size_t)b * N + qrow) * H + h) * D + hq * 8;
    qf[0] = *(const bf16x8*)qp;
    qf[1] = *(const bf16x8*)(qp + 32);
  }

  f32x4 oacc[4] = {};
  float m_run = -1e30f, l_run = 0.f;

  auto stage = [&](int buf, int l0) {
#pragma unroll
    for (int r = 0; r < 4; ++r) {
      const int rb = (w * 4 + r) * 8;          // wave-uniform; 8 rows of 128B
      const int row = rb + (l >> 3);
      const int j = (l & 7) ^ (row & 7);
      glds16(kb + (((size_t)b * L + l0 + row) * H + h) * D + j * 8,
             (char*)&ldsK[buf][0] + rb * 128);
    }
#pragma unroll
    for (int r = 0; r < 4; ++r) {
      const int rb = (w * 4 + r) * 4;          // wave-uniform; 4 rows of 256B
      const int row = rb + (l >> 4);
      const int j = (l & 15) ^ (row & 15);
      glds16(vT + ((size_t)(b * H + h) * D + row) * L + l0 + j * 8,
             (char*)&ldsV[buf][0] + rb * 256);
    }
  };

  stage(0, 0);

  for (int t = 0; t < L / KB; ++t) {
    const int buf = t & 1;
    if (t < L / KB - 1) {
      stage(buf ^ 1, (t + 1) * KB);
      asm volatile("s_waitcnt vmcnt(8)" ::: "memory");  // tile t's 8 loads done
    } else {
      asm volatile("s_waitcnt vmcnt(0)" ::: "memory");
    }
    SB(); __builtin_amdgcn_s_barrier(); SB();

    // S^T = mfma(K, Q): lane holds S[q=lane&15][l = 16c + 4*hq + i]
    f32x4 sacc[8] = {};
#pragma unroll
    for (int c = 0; c < 8; ++c) {
      const int rt = c * 16 + (l & 15);     // K-row (l index)
#pragma unroll
      for (int ks = 0; ks < 2; ++ks) {
        const int j = ks * 4 + hq;
        bf16x8 kf = *(const bf16x8*)((const char*)&ldsK[buf][0] + rt * 128 + ((j ^ (rt & 7)) << 4));
        sacc[c] = MFMA16(kf, qf[ks], sacc[c]);
      }
    }

    // in-lane online softmax (exp2 space; SCALE*log2e folded into q)
    float mt = -1e30f;
#pragma unroll
    for (int c = 0; c < 8; ++c)
#pragma unroll
      for (int i = 0; i < 4; ++i) mt = fmaxf(mt, sacc[c][i]);
    mt = fmaxf(mt, __shfl_xor(mt, 16, 64));
    mt = fmaxf(mt, __shfl_xor(mt, 32, 64));
    const float mn = fmaxf(m_run, mt);
    const float corr = __builtin_amdgcn_exp2f(m_run - mn);
    float rs = 0.f;
#pragma unroll
    for (int c = 0; c < 8; ++c)
#pragma unroll
      for (int i = 0; i < 4; ++i) {
        const float p = __builtin_amdgcn_exp2f(sacc[c][i] - mn);
        sacc[c][i] = p;
        rs += p;
      }
    rs += __shfl_xor(rs, 16, 64);
    rs += __shfl_xor(rs, 32, 64);
    l_run = l_run * corr + rs;
    m_run = mn;

    // broadcast corr to O-layout rows (O row q_local = 4*hq + i; corr lives in lane q_local)
    float corrO[4];
#pragma unroll
    for (int i = 0; i < 4; ++i) corrO[i] = __shfl(corr, hq * 4 + i, 64);
#pragma unroll
    for (int c = 0; c < 4; ++c)
#pragma unroll
      for (int i = 0; i < 4; ++i) oacc[c][i] *= corrO[i];

    // P A-fragments directly from sacc: pf[ks] = {sacc[2ks][0..3], sacc[2ks+1][0..3]}
    bf16x8 pf[4];
#pragma unroll
    for (int ks = 0; ks < 4; ++ks)
#pragma unroll
      for (int i = 0; i < 4; ++i) {
        pf[ks][i]     = (__bf16)sacc[2 * ks][i];
        pf[ks][4 + i] = (__bf16)sacc[2 * ks + 1][i];
      }

    // O += P V.  B-frag: lane (d=lane&15, hq) needs V[l=32ks+16a+4hq+i][d], a=0,1
    //   -> two b64 reads: chunk 4ks+2a+(hq>>1), byte-in-chunk (hq&1)*8
#pragma unroll
    for (int c = 0; c < 4; ++c) {
      const int rt = c * 16 + (l & 15);     // V-row (d index)
      const char* vrow = (const char*)&ldsV[buf][0] + rt * 256 + ((hq & 1) << 3);
#pragma unroll
      for (int ks = 0; ks < 4; ++ks) {
        const int j0 = ks * 4 + (hq >> 1);
        bf16x4 va = *(const bf16x4*)(vrow + ((j0 ^ (rt & 15)) << 4));
        bf16x4 vb = *(const bf16x4*)(vrow + (((j0 + 2) ^ (rt & 15)) << 4));
        bf16x8 vf = __builtin_shufflevector(va, vb, 0, 1, 2, 3, 4, 5, 6, 7);
        oacc[c] = MFMA16(pf[ks], vf, oacc[c]);
      }
    }
    SB(); __builtin_amdgcn_s_barrier(); SB();  // all waves done reading buf
  }

  // epilogue: O / l_run -> ao (B,N,H,D)
  float lr[4];
#pragma unroll
  for (int i = 0; i < 4; ++i) lr[i] = __shfl(l_run, hq * 4 + i, 64);
#pragma unroll
  for (int c = 0; c < 4; ++c)
#pragma unroll
    for (int i = 0; i < 4; ++i) {
      const int n = n0 + w * 16 + hq * 4 + i;
      const int d = c * 16 + (l & 15);
      ao[(((size_t)b * N + n) * H + h) * D + d] = f2bf(oacc[c][i] / lr[i]);
    }
}

// ---------------------------------------------------------------- launch
extern "C" void kernel_launch(void* const* d_in, const int* in_sizes, int n_in,
                              void* d_out, int out_size, void* d_ws, size_t ws_size,
                              hipStream_t stream) {
  const float* x  = (const float*)d_in[0];  // (2,1024,1024)
  const float* y  = (const float*)d_in[1];  // (2,4096,1024)
  const float* Wq = (const float*)d_in[2];
  const float* Wk = (const float*)d_in[3];
  const float* Wv = (const float*)d_in[4];
  const float* Wp = (const float*)d_in[5];
  const float* bp = (const float*)d_in[6];
  float* out = (float*)d_out;

  const size_t M1 = 1u << 20;
  ushort* wsb = (ushort*)d_ws;
  ushort* xb  = wsb;             // 2M elems
  ushort* yb  = wsb + 2 * M1;    // 8M
  ushort* wqb = wsb + 10 * M1;   // 1M
  ushort* wkb = wsb + 11 * M1;
  ushort* wvb = wsb + 12 * M1;
  ushort* wpb = wsb + 13 * M1;
  ushort* qbf = wsb + 14 * M1;   // 2M
  ushort* kbf = wsb + 16 * M1;   // 8M
  ushort* vtb = wsb + 24 * M1;   // 8M
  ushort* aob = wsb + 32 * M1;   // 2M  (total 34M elems = 68 MB)

  cvt_xy<<<10240, 256, 0, stream>>>(x, y, xb, yb);
  cvt_w<<<4096, 256, 0, stream>>>(Wq, Wk, Wv, Wp, wqb, wkb, wvb, wpb);

  const float qscale = 0.125f * 1.4426950408889634f;  // SCALE * log2(e)
  gemm_bt<0, 64, 64><<<dim3(32, 16), 256, 0, stream>>>(xb, wqb, qbf, 1024, qscale, nullptr);
  gemm_bt<0, 128, 128><<<dim3(64, 8), 256, 0, stream>>>(yb, wkb, kbf, 1024, 1.0f, nullptr);
  gemm_bt<1, 128, 128><<<dim3(64, 8), 256, 0, stream>>>(yb, wvb, vtb, 1024, 1.0f, nullptr);

  attn_fused<<<512, 256, 0, stream>>>(qbf, kbf, vtb, aob);

  gemm_bt<2, 64, 64><<<dim3(32, 16), 256, 0, stream>>>(aob, wpb, out, 1024, 1.0f, bp);
}

// Round 5
// 249.992 us; speedup vs baseline: 1.3588x; 1.0505x over previous
//
#include <hip/hip_runtime.h>
#include <hip/hip_bf16.h>
#include <stdint.h>

typedef __bf16 bf16x8 __attribute__((ext_vector_type(8)));
typedef __bf16 bf16x4 __attribute__((ext_vector_type(4)));
typedef float f32x4 __attribute__((ext_vector_type(4)));

#define MFMA16(a, b, c) __builtin_amdgcn_mfma_f32_16x16x32_bf16((a), (b), (c), 0, 0, 0)
#define SB() __builtin_amdgcn_sched_barrier(0)

// fp32 -> bf16 RNE
__device__ __forceinline__ ushort f2bf(float f) {
  union { float f; uint32_t u; } a; a.f = f;
  uint32_t u = a.u;
  return (ushort)((u + 0x7fffu + ((u >> 16) & 1u)) >> 16);
}

// global -> LDS direct DMA, 16B per lane. LDS dest must be wave-uniform.
__device__ __forceinline__ void glds16(const void* g, void* l) {
  __builtin_amdgcn_global_load_lds(
      (const __attribute__((address_space(1))) uint32_t*)g,
      (__attribute__((address_space(3))) uint32_t*)l, 16, 0, 0);
}

// ---------------------------------------------------------------- converts
__global__ __launch_bounds__(256) void cvt_xy(const float* __restrict__ x,
                                              const float* __restrict__ y,
                                              ushort* __restrict__ xb,
                                              ushort* __restrict__ yb) {
  const int bid = blockIdx.x;
  const float* in;
  ushort* out;
  int i;
  if (bid < 2048) { in = x; out = xb; i = bid * 1024 + threadIdx.x * 4; }
  else            { in = y; out = yb; i = (bid - 2048) * 1024 + threadIdx.x * 4; }
  float4 v = *(const float4*)(in + i);
  ushort4 o;
  o.x = f2bf(v.x); o.y = f2bf(v.y); o.z = f2bf(v.z); o.w = f2bf(v.w);
  *(ushort4*)(out + i) = o;
}

__global__ __launch_bounds__(256) void cvt_w(
    const float* __restrict__ a, const float* __restrict__ b,
    const float* __restrict__ c, const float* __restrict__ d,
    ushort* __restrict__ oa, ushort* __restrict__ ob,
    ushort* __restrict__ oc, ushort* __restrict__ od) {
  const int bid = blockIdx.x;
  const int sel = bid >> 10;
  const int i = (bid & 1023) * 1024 + threadIdx.x * 4;
  const float* in = (sel == 0) ? a : (sel == 1) ? b : (sel == 2) ? c : d;
  ushort* out = (sel == 0) ? oa : (sel == 1) ? ob : (sel == 2) ? oc : od;
  float4 v = *(const float4*)(in + i);
  ushort4 o;
  o.x = f2bf(v.x); o.y = f2bf(v.y); o.z = f2bf(v.z); o.w = f2bf(v.w);
  *(ushort4*)(out + i) = o;
}

// ---------------------------------------------------------------- GEMM (B^T)
// out[m][n] = sum_k A[m][k] * Bw[n][k].  Double-buffered LDS, T3-min pipeline.
// EPI 0: bf16 out [M][1024], * scale
// EPI 1: bf16 out scattered to vT layout (B,H,D,L) = (2,16,64,4096)  (128x128 only)
// EPI 2: f32 out [M][1024] + bias
template <int EPI, int BM, int BN>
__global__ __launch_bounds__(256) void gemm_bt(
    const ushort* __restrict__ A, const ushort* __restrict__ Bw,
    void* __restrict__ Cout, int K, float scale, const float* __restrict__ bias) {
  constexpr int NN = 1024;
  constexpr int WM = BM / 2, WN = BN / 2;
  constexpr int AM = WM / 16, BNF = WN / 16;
  __shared__ ushort ldsA[2][BM * 32];
  __shared__ ushort ldsB[2][BN * 32];
  __shared__ ushort ldsT[(EPI == 1) ? (4 * 64 * 64) : 8];

  const int tid = threadIdx.x;
  const int w = tid >> 6, l = tid & 63;
  const int wm = w >> 1, wn = w & 1;
  const int m0 = blockIdx.x * BM, n0 = blockIdx.y * BN;

  f32x4 acc[AM][BNF] = {};

  const int srow = l >> 2;      // 16 rows per wave-issue (4 chunks of 16B per 64B row)
  const int schunk = l & 3;

  auto stage = [&](int buf, int kt) {
#pragma unroll
    for (int r = 0; r < BM / 64; ++r) {
      const int rb = r * 64 + w * 16;           // wave-uniform row base
      const int row = rb + srow;
      const int j = schunk ^ ((row >> 1) & 3);  // pre-swizzled global source chunk
      glds16(A + (size_t)(m0 + row) * K + kt + j * 8, (char*)&ldsA[buf][0] + rb * 64);
    }
#pragma unroll
    for (int r = 0; r < BN / 64; ++r) {
      const int rb = r * 64 + w * 16;
      const int row = rb + srow;
      const int j = schunk ^ ((row >> 1) & 3);
      glds16(Bw + (size_t)(n0 + row) * K + kt + j * 8, (char*)&ldsB[buf][0] + rb * 64);
    }
  };

  const int nt = K / 32;
  stage(0, 0);
  asm volatile("s_waitcnt vmcnt(0)" ::: "memory");
  SB(); __builtin_amdgcn_s_barrier(); SB();

  for (int t = 0; t < nt; ++t) {
    const int buf = t & 1;
    if (t + 1 < nt) stage(buf ^ 1, (t + 1) * 32);
    bf16x8 af[AM], bfr[BNF];
#pragma unroll
    for (int a = 0; a < AM; ++a) {
      const int rt = wm * WM + a * 16 + (l & 15);
      const int j = (l >> 4) ^ ((rt >> 1) & 3);
      af[a] = *(const bf16x8*)((const char*)&ldsA[buf][0] + rt * 64 + j * 16);
    }
#pragma unroll
    for (int bx = 0; bx < BNF; ++bx) {
      const int rt = wn * WN + bx * 16 + (l & 15);
      const int j = (l >> 4) ^ ((rt >> 1) & 3);
      bfr[bx] = *(const bf16x8*)((const char*)&ldsB[buf][0] + rt * 64 + j * 16);
    }
#pragma unroll
    for (int am = 0; am < AM; ++am)
#pragma unroll
      for (int bn = 0; bn < BNF; ++bn)
        acc[am][bn] = MFMA16(af[am], bfr[bn], acc[am][bn]);
    if (t + 1 < nt) {
      asm volatile("s_waitcnt vmcnt(0)" ::: "memory");
      SB(); __builtin_amdgcn_s_barrier(); SB();
    }
  }

  if constexpr (EPI == 0) {
#pragma unroll
    for (int am = 0; am < AM; ++am)
#pragma unroll
      for (int bn = 0; bn < BNF; ++bn)
#pragma unroll
        for (int i = 0; i < 4; ++i) {
          const int row = m0 + wm * WM + am * 16 + (l >> 4) * 4 + i;
          const int col = n0 + wn * WN + bn * 16 + (l & 15);
          ((ushort*)Cout)[(size_t)row * NN + col] = f2bf(acc[am][bn][i] * scale);
        }
  } else if constexpr (EPI == 2) {
#pragma unroll
    for (int am = 0; am < AM; ++am)
#pragma unroll
      for (int bn = 0; bn < BNF; ++bn)
#pragma unroll
        for (int i = 0; i < 4; ++i) {
          const int row = m0 + wm * WM + am * 16 + (l >> 4) * 4 + i;
          const int col = n0 + wn * WN + bn * 16 + (l & 15);
          ((float*)Cout)[(size_t)row * NN + col] = acc[am][bn][i] + bias[col];
        }
  } else {
    // EPI 1: transpose 64x64 wave tile in LDS, then coalesced stores along L.
    ushort* tp = ldsT + w * 4096;
#pragma unroll
    for (int am = 0; am < AM; ++am)
#pragma unroll
      for (int bn = 0; bn < BNF; ++bn)
#pragma unroll
        for (int i = 0; i < 4; ++i) {
          const int ml = am * 16 + (l >> 4) * 4 + i;
          const int cl = bn * 16 + (l & 15);
          tp[cl * 64 + ml] = f2bf(acc[am][bn][i]);
        }
    __syncthreads();
#pragma unroll
    for (int it = 0; it < 8; ++it) {
      const int cl = it * 8 + (l >> 3);
      const int mc = l & 7;
      bf16x8 vv = *(const bf16x8*)(tp + cl * 64 + mc * 8);
      const int gcol = n0 + wn * WN + cl;   // 0..1023 -> (h,d)
      const int gm = m0 + wm * WM + mc * 8; // 0..8191 -> (b,l_)
      const int b = gm >> 12;
      const int l_ = gm & 4095;
      const int h = gcol >> 6, d = gcol & 63;
      *(bf16x8*)((ushort*)Cout + (((size_t)b * 16 + h) * 64 + d) * 4096 + l_) = vv;
    }
  }
}

// ---------------------------------------------------------------- fused attention
// Swapped QK^T with lambda row-permutation: MFMA c takes K-rows
//   rt = 32*(c>>1) + 4*(c&1) + 8*(m>>2) + (m&3)   (m = lane&15)
// so lane (q,hq) gets sacc[2ks][i] = S[q][32ks+8hq+i], sacc[2ks+1][i] =
// S[q][32ks+8hq+4+i] -> P A-frag = register concat (identity hardware-k) and
// the V B-frag is a single contiguous b128 (conflict-free, round-3 pattern).
// K swizzle sigma(rt) = (rt&3) + 4*((rt>>3)&1) keeps 8 lanes/granule uniform.
__global__ __launch_bounds__(256) void attn_fused(
    const ushort* __restrict__ qb, const ushort* __restrict__ kb,
    const ushort* __restrict__ vT, ushort* __restrict__ ao) {
  constexpr int H = 16, D = 64, L = 4096, N = 1024, KB = 128;
  __shared__ ushort ldsK[2][KB * 64];   // [l][d]  128B rows, 8 chunks, swz sigma
  __shared__ ushort ldsV[2][64 * KB];   // [d][l]  256B rows, 16 chunks, swz ^(row&15)

  const int tid = threadIdx.x, w = tid >> 6, l = tid & 63;
  // XCD swizzle: 512 blocks = 8 XCDs x 64; each XCD owns 4 (b,h) values.
  const int wg = blockIdx.x;
  const int v = (wg & 7) * 64 + (wg >> 3);
  const int bh = v >> 4;
  const int n0 = (v & 15) * 64;
  const int b = bh >> 4, h = bh & 15;
  const int hq = l >> 4;   // lane quadrant
  const int m = l & 15;

  // Q fragments (B-operand): lane holds q-row = n0 + w*16 + (lane&15)
  bf16x8 qf[2];
  {
    const int qrow = n0 + w * 16 + m;
    const ushort* qp = qb + (((size_t)b * N + qrow) * H + h) * D + hq * 8;
    qf[0] = *(const bf16x8*)qp;
    qf[1] = *(const bf16x8*)(qp + 32);
  }

  f32x4 oacc[4] = {};
  float m_run = -1e30f, l_run = 0.f;

  auto stage = [&](int buf, int l0) {
#pragma unroll
    for (int r = 0; r < 4; ++r) {
      const int rb = (w * 4 + r) * 8;          // wave-uniform; 8 rows of 128B
      const int row = rb + (l >> 3);
      const int sk = (row & 3) + 4 * ((row >> 3) & 1);   // sigma(row)
      const int j = (l & 7) ^ sk;
      glds16(kb + (((size_t)b * L + l0 + row) * H + h) * D + j * 8,
             (char*)&ldsK[buf][0] + rb * 128);
    }
#pragma unroll
    for (int r = 0; r < 4; ++r) {
      const int rb = (w * 4 + r) * 4;          // wave-uniform; 4 rows of 256B
      const int row = rb + (l >> 4);
      const int j = (l & 15) ^ (row & 15);
      glds16(vT + ((size_t)(b * H + h) * D + row) * L + l0 + j * 8,
             (char*)&ldsV[buf][0] + rb * 256);
    }
  };

  stage(0, 0);

  // per-lane lambda constants: rt = 32*(c>>1) + 4*(c&1) + rtl;  sigma(rt) = skl
  const int rtl = 8 * (m >> 2) + (m & 3);
  const int skl = (m & 3) + 4 * ((m >> 2) & 1);

  for (int t = 0; t < L / KB; ++t) {
    const int buf = t & 1;
    if (t < L / KB - 1) {
      stage(buf ^ 1, (t + 1) * KB);
      asm volatile("s_waitcnt vmcnt(8)" ::: "memory");  // tile t's 8 loads done
    } else {
      asm volatile("s_waitcnt vmcnt(0)" ::: "memory");
    }
    SB(); __builtin_amdgcn_s_barrier(); SB();

    // S^T = mfma(K, Q), lambda-ordered A-rows
    f32x4 sacc[8] = {};
    __builtin_amdgcn_s_setprio(1);
#pragma unroll
    for (int c = 0; c < 8; ++c) {
      const int rt = 32 * (c >> 1) + 4 * (c & 1) + rtl;
#pragma unroll
      for (int ks = 0; ks < 2; ++ks) {
        const int j = ks * 4 + hq;
        bf16x8 kf = *(const bf16x8*)((const char*)&ldsK[buf][0] + rt * 128 + ((j ^ skl) << 4));
        sacc[c] = MFMA16(kf, qf[ks], sacc[c]);
      }
    }
    __builtin_amdgcn_s_setprio(0);

    // in-lane online softmax (exp2 space; SCALE*log2e folded into q)
    float mt = -1e30f;
#pragma unroll
    for (int c = 0; c < 8; ++c)
#pragma unroll
      for (int i = 0; i < 4; ++i) mt = fmaxf(mt, sacc[c][i]);
    mt = fmaxf(mt, __shfl_xor(mt, 16, 64));
    mt = fmaxf(mt, __shfl_xor(mt, 32, 64));
    // defer-max (T13): only rescale when some row's max grew by > 8 (exp2 space)
    if (!__all(mt <= m_run + 8.f)) {
      const float mn = fmaxf(m_run, mt);
      const float corr = __builtin_amdgcn_exp2f(m_run - mn);
      float corrO[4];
#pragma unroll
      for (int i = 0; i < 4; ++i) corrO[i] = __shfl(corr, hq * 4 + i, 64);
#pragma unroll
      for (int c = 0; c < 4; ++c)
#pragma unroll
        for (int i = 0; i < 4; ++i) oacc[c][i] *= corrO[i];
      l_run *= corr;
      m_run = mn;
    }
    float rs = 0.f;
#pragma unroll
    for (int c = 0; c < 8; ++c)
#pragma unroll
      for (int i = 0; i < 4; ++i) {
        const float p = __builtin_amdgcn_exp2f(sacc[c][i] - m_run);
        sacc[c][i] = p;
        rs += p;
      }
    rs += __shfl_xor(rs, 16, 64);
    rs += __shfl_xor(rs, 32, 64);
    l_run += rs;

    // P A-fragments directly from sacc (identity hardware-k under lambda)
    bf16x8 pf[4];
#pragma unroll
    for (int ks = 0; ks < 4; ++ks)
#pragma unroll
      for (int i = 0; i < 4; ++i) {
        pf[ks][i]     = (__bf16)sacc[2 * ks][i];
        pf[ks][4 + i] = (__bf16)sacc[2 * ks + 1][i];
      }

    // O += P V.  B-frag: single b128, V[l = 32ks+8hq .. +7][d], chunk 4ks+hq.
    __builtin_amdgcn_s_setprio(1);
#pragma unroll
    for (int c = 0; c < 4; ++c) {
      const int rt = c * 16 + m;            // V-row (d index)
#pragma unroll
      for (int ks = 0; ks < 4; ++ks) {
        const int j = ks * 4 + hq;
        bf16x8 vf = *(const bf16x8*)((const char*)&ldsV[buf][0] + rt * 256 + ((j ^ (rt & 15)) << 4));
        oacc[c] = MFMA16(pf[ks], vf, oacc[c]);
      }
    }
    __builtin_amdgcn_s_setprio(0);
    SB(); __builtin_amdgcn_s_barrier(); SB();  // all waves done reading buf
  }

  // epilogue: O / l_run -> ao (B,N,H,D)
  float lr[4];
#pragma unroll
  for (int i = 0; i < 4; ++i) lr[i] = __shfl(l_run, hq * 4 + i, 64);
#pragma unroll
  for (int c = 0; c < 4; ++c)
#pragma unroll
    for (int i = 0; i < 4; ++i) {
      const int n = n0 + w * 16 + hq * 4 + i;
      const int d = c * 16 + m;
      ao[(((size_t)b * N + n) * H + h) * D + d] = f2bf(oacc[c][i] / lr[i]);
    }
}

// ---------------------------------------------------------------- launch
extern "C" void kernel_launch(void* const* d_in, const int* in_sizes, int n_in,
                              void* d_out, int out_size, void* d_ws, size_t ws_size,
                              hipStream_t stream) {
  const float* x  = (const float*)d_in[0];  // (2,1024,1024)
  const float* y  = (const float*)d_in[1];  // (2,4096,1024)
  const float* Wq = (const float*)d_in[2];
  const float* Wk = (const float*)d_in[3];
  const float* Wv = (const float*)d_in[4];
  const float* Wp = (const float*)d_in[5];
  const float* bp = (const float*)d_in[6];
  float* out = (float*)d_out;

  const size_t M1 = 1u << 20;
  ushort* wsb = (ushort*)d_ws;
  ushort* xb  = wsb;             // 2M elems
  ushort* yb  = wsb + 2 * M1;    // 8M
  ushort* wqb = wsb + 10 * M1;   // 1M
  ushort* wkb = wsb + 11 * M1;
  ushort* wvb = wsb + 12 * M1;
  ushort* wpb = wsb + 13 * M1;
  ushort* qbf = wsb + 14 * M1;   // 2M
  ushort* kbf = wsb + 16 * M1;   // 8M
  ushort* vtb = wsb + 24 * M1;   // 8M
  ushort* aob = wsb + 32 * M1;   // 2M  (total 34M elems = 68 MB)

  cvt_xy<<<10240, 256, 0, stream>>>(x, y, xb, yb);
  cvt_w<<<4096, 256, 0, stream>>>(Wq, Wk, Wv, Wp, wqb, wkb, wvb, wpb);

  const float qscale = 0.125f * 1.4426950408889634f;  // SCALE * log2(e)
  gemm_bt<0, 64, 64><<<dim3(32, 16), 256, 0, stream>>>(xb, wqb, qbf, 1024, qscale, nullptr);
  gemm_bt<0, 128, 128><<<dim3(64, 8), 256, 0, stream>>>(yb, wkb, kbf, 1024, 1.0f, nullptr);
  gemm_bt<1, 128, 128><<<dim3(64, 8), 256, 0, stream>>>(yb, wvb, vtb, 1024, 1.0f, nullptr);

  attn_fused<<<512, 256, 0, stream>>>(qbf, kbf, vtb, aob);

  gemm_bt<2, 64, 64><<<dim3(32, 16), 256, 0, stream>>>(aob, wpb, out, 1024, 1.0f, bp);
}